// Round 10
// baseline (446.472 us; speedup 1.0000x reference)
//
#include <hip/hip_runtime.h>

constexpr int   FEAT   = 128;
constexpr int   BATCH  = 512;
constexpr int   NNEG   = 4096;
constexpr long  NDATA  = 1200000;
constexpr int   CHUNKS = 8;                       // blocks per row in negsim
constexpr int   NCOPYB = 2048;                    // copy blocks (8192 waves)
constexpr long  NSRCG  = NDATA * FEAT / 4;        // 38,400,000 aligned src groups
constexpr long  GMAXO  = NSRCG;                   // out groups 1..NSRCG-1 are full
constexpr float INV_TEMP = 14.285714285714286f;   // 1/0.07 (max possible logit)
constexpr float LOG2E    = 1.4426950408889634f;
constexpr float LN2      = 0.6931471805599453f;
constexpr float K1       = INV_TEMP * LOG2E;      // logit->exp2 scale

typedef float f4 __attribute__((ext_vector_type(4)));

// ---------------- prep: normalize s,t and compute pos logit ----------------
__global__ __launch_bounds__(128) void prep_kernel(
    const float* __restrict__ sf, const float* __restrict__ tf,
    float* __restrict__ s_n, float* __restrict__ t_n, float* __restrict__ pos) {
  const int b = blockIdx.x, t = threadIdx.x;
  const float sv = sf[b * FEAT + t];
  const float tv = tf[b * FEAT + t];
  float ss = sv * sv, tt = tv * tv, st = sv * tv;
#pragma unroll
  for (int m = 1; m < 64; m <<= 1) {
    ss += __shfl_xor(ss, m);
    tt += __shfl_xor(tt, m);
    st += __shfl_xor(st, m);
  }
  __shared__ float sh[6];
  if ((t & 63) == 0) {
    const int w = t >> 6;
    sh[w * 3 + 0] = ss; sh[w * 3 + 1] = tt; sh[w * 3 + 2] = st;
  }
  __syncthreads();
  ss = sh[0] + sh[3]; tt = sh[1] + sh[4]; st = sh[2] + sh[5];
  const float snorm = fmaxf(sqrtf(ss), 1e-12f);
  const float tnorm = fmaxf(sqrtf(tt), 1e-12f);
  s_n[b * FEAT + t] = sv / snorm;
  t_n[b * FEAT + t] = tv / tnorm;
  if (t == 0) pos[b] = st / (snorm * tnorm) * INV_TEMP;
}

// ------------- negsim (standalone, COLD gather from HBM) -------------------
// 2 k's per wave-load: lanes 0-31 carry k0, lanes 32-63 carry k1, each lane
// a float4 of features. One dwordx4 = one 512B row per half-wave (coalesced,
// 8 sequential lines per row -> streams at HBM rate). Idx loads pipelined
// one iteration ahead; 5 shfl_xor levels confined to 32-lane halves.
__global__ __launch_bounds__(256) void negsim_kernel(
    const float* __restrict__ neg, const int* __restrict__ nidx,
    const float* __restrict__ s_n, float* __restrict__ sumexp) {
  __shared__ float part[4];
  const int blk   = blockIdx.x;
  const int b     = blk >> 3;               // batch row of s
  const int chunk = blk & (CHUNKS - 1);     // which 512-k slice
  const int t     = threadIdx.x;
  const int lane  = t & 63;
  const int w     = t >> 6;                 // wave id (0..3)
  const int half  = lane >> 5;              // 0: k-even, 1: k-odd
  const int fo    = (lane & 31) * 4;        // this lane's feature offset
  const f4 s4 = *(const f4*)(s_n + b * FEAT + fo);
  const int kbase = b * NNEG + chunk * (NNEG / CHUNKS) + w * 128;
  float acc = 0.f;
  int off[8];
#pragma unroll
  for (int u = 0; u < 8; ++u)
    off[u] = nidx[kbase + 2 * u + half] * FEAT;
  for (int k0 = 0; k0 < 128; k0 += 16) {    // 8 row-loads in flight (16 k)
    int noff[8];
    if (k0 + 16 < 128) {
#pragma unroll
      for (int u = 0; u < 8; ++u)           // prefetch next iteration's idx
        noff[u] = nidx[kbase + k0 + 16 + 2 * u + half] * FEAT;
    }
    f4 v[8];
#pragma unroll
    for (int u = 0; u < 8; ++u)
      v[u] = *(const f4*)(neg + (long)off[u] + fo);
    float p[8];
#pragma unroll
    for (int u = 0; u < 8; ++u) {
      const f4 m = v[u] * s4;
      p[u] = (m.x + m.y) + (m.z + m.w);
    }
#pragma unroll
    for (int ms = 1; ms <= 16; ms <<= 1) {  // 5 levels, stays within halves
#pragma unroll
      for (int u = 0; u < 8; ++u) p[u] += __shfl_xor(p[u], ms);
    }
    // exp(logit - C) = exp2(cos*K1 - K1); each k's term lands in 32 lanes
#pragma unroll
    for (int u = 0; u < 8; ++u) acc += exp2f(fmaf(p[u], K1, -K1));
#pragma unroll
    for (int u = 0; u < 8; ++u) off[u] = noff[u];
  }
  acc *= (1.0f / 32.0f);                    // each k counted in 32 lanes
#pragma unroll
  for (int m = 1; m < 64; m <<= 1) acc += __shfl_xor(acc, m);
  if (lane == 0) part[w] = acc;
  __syncthreads();
  if (t == 0)
    sumexp[blk] = part[0] + part[1] + part[2] + part[3];
}

// ------ copyloss: block 0 = loss; blocks 1..NCOPYB = aligned copy ----------
// Copy: ALIGNED f4 cached loads + in-register realign (one shfl_up) +
// ALIGNED f4 nontemporal stores. Each wave owns a contiguous chunk; per iter
// lanes 1..63 store 63 groups; lane-overlap re-load hits L1. No split loads,
// no partial-line NT writes.
__global__ __launch_bounds__(256) void copyloss_kernel(
    const float* __restrict__ neg, const float* __restrict__ pos,
    const float* __restrict__ sumexp, float* __restrict__ out) {
  const int t = threadIdx.x;
  if (blockIdx.x == 0) {                    // ---- loss ----
    float lsum = 0.f;
#pragma unroll
    for (int r = t; r < BATCH; r += 256) {
      const float p = pos[r];
      float tot = exp2f(fmaf(p, LOG2E, -K1));  // exp(p - C)
#pragma unroll
      for (int c = 0; c < CHUNKS; ++c) tot += sumexp[r * CHUNKS + c];
      lsum += INV_TEMP + log2f(tot) * LN2 - p; // C + ln(tot) - p
    }
#pragma unroll
    for (int m = 1; m < 64; m <<= 1) lsum += __shfl_xor(lsum, m);
    __shared__ float sh[4];
    if ((t & 63) == 0) sh[t >> 6] = lsum;
    __syncthreads();
    if (t == 0) {
      out[0] = (sh[0] + sh[1] + sh[2] + sh[3]) / (float)BATCH;
      const long n = NDATA * (long)FEAT;     // head + tail scalars
      out[1] = neg[0]; out[2] = neg[1]; out[3] = neg[2];
      out[n] = neg[n - 1];
    }
    return;
  }
  const f4* __restrict__ ps = (const f4*)neg;
  f4* __restrict__ po = (f4*)out;           // out 16B-aligned; group g = out[4g..4g+3]
  const int lane = t & 63;
  const int wid  = (blockIdx.x - 1) * 4 + (t >> 6);        // 0..NCOPYB*4-1
  constexpr long NWAVE = (long)NCOPYB * 4;
  constexpr long PER   = (GMAXO - 1 + NWAVE - 1) / NWAVE;  // groups per wave
  long base = 1 + (long)wid * PER;
  const long gend = (base + PER < GMAXO) ? base + PER : GMAXO;
  if (base >= gend) return;
  long src = base - 1 + lane;               // pipeline one load ahead
  f4 cur = ps[src < NSRCG ? src : NSRCG - 1];
  while (base < gend) {
    const long nbase = base + 63;
    f4 nxt = {0.f, 0.f, 0.f, 0.f};
    if (nbase < gend) {
      const long ns = nbase - 1 + lane;
      nxt = ps[ns < NSRCG ? ns : NSRCG - 1];
    }
    const float pw = __shfl_up(cur.w, 1);
    const long g = base + lane - 1;
    if (lane >= 1 && g < gend) {
      f4 v; v.x = pw; v.y = cur.x; v.z = cur.y; v.w = cur.z;
      __builtin_nontemporal_store(v, po + g);
    }
    cur = nxt;
    base = nbase;
  }
}

// ------------- EMA scatter update with last-writer-wins --------------------
__global__ __launch_bounds__(128) void update_kernel(
    const float* __restrict__ neg, const float* __restrict__ t_n,
    const int* __restrict__ indices, float* __restrict__ dst) {
  const int b = blockIdx.x, t = threadIdx.x;
  __shared__ int sidx[BATCH];
  __shared__ int flag;
  if (t == 0) flag = 0;
  for (int j = t; j < BATCH; j += 128) sidx[j] = indices[j];
  __syncthreads();
  const int idx = sidx[b];
  int later = 0;
  for (int j = t; j < BATCH; j += 128)
    if (j > b && sidx[j] == idx) later = 1;
  if (later) flag = 1;  // benign same-value race
  __syncthreads();
  if (flag) return;     // a later batch element writes this row (last wins)
  const float u = 0.5f * neg[(long)idx * FEAT + t] + 0.5f * t_n[b * FEAT + t];
  float uu = u * u;
#pragma unroll
  for (int m = 1; m < 64; m <<= 1) uu += __shfl_xor(uu, m);
  __shared__ float sh2[2];
  if ((t & 63) == 0) sh2[t >> 6] = uu;
  __syncthreads();
  const float nrm = fmaxf(sqrtf(sh2[0] + sh2[1]), 1e-12f);
  dst[(long)idx * FEAT + t] = u / nrm;
}

extern "C" void kernel_launch(void* const* d_in, const int* in_sizes, int n_in,
                              void* d_out, int out_size, void* d_ws, size_t ws_size,
                              hipStream_t stream) {
  const float* student   = (const float*)d_in[0];
  const float* teacher   = (const float*)d_in[1];
  const float* negatives = (const float*)d_in[2];
  const int*   indices   = (const int*)d_in[3];
  const int*   neg_idx   = (const int*)d_in[4];
  float* out = (float*)d_out;

  float* ws     = (float*)d_ws;
  float* s_n    = ws;                        // [512*128]
  float* t_n    = s_n + BATCH * FEAT;        // [512*128]
  float* pos    = t_n + BATCH * FEAT;        // [512]
  float* sumexp = pos + BATCH;               // [512*CHUNKS]

  prep_kernel<<<BATCH, 128, 0, stream>>>(student, teacher, s_n, t_n, pos);
  negsim_kernel<<<BATCH * CHUNKS, 256, 0, stream>>>(negatives, neg_idx, s_n, sumexp);
  copyloss_kernel<<<1 + NCOPYB, 256, 0, stream>>>(negatives, pos, sumexp, out);
  update_kernel<<<BATCH, 128, 0, stream>>>(negatives, t_n, indices, out + 1);
}

// Round 11
// 381.070 us; speedup vs baseline: 1.1716x; 1.1716x over previous
//
#include <hip/hip_runtime.h>

constexpr int   FEAT   = 128;
constexpr int   BATCH  = 512;
constexpr int   NNEG   = 4096;
constexpr long  NDATA  = 1200000;
constexpr int   CHUNKS = 8;                       // blocks per row in negsim
constexpr int   NCOPY  = 1024;                    // persistent copy blocks
constexpr float INV_TEMP = 14.285714285714286f;   // 1/0.07 (max possible logit)
constexpr float LOG2E    = 1.4426950408889634f;
constexpr float LN2      = 0.6931471805599453f;
constexpr float K1       = INV_TEMP * LOG2E;      // logit->exp2 scale

typedef float f4 __attribute__((ext_vector_type(4)));

// ---------------- prep: normalize s,t and compute pos logit ----------------
__global__ __launch_bounds__(128) void prep_kernel(
    const float* __restrict__ sf, const float* __restrict__ tf,
    float* __restrict__ s_n, float* __restrict__ t_n, float* __restrict__ pos) {
  const int b = blockIdx.x, t = threadIdx.x;
  const float sv = sf[b * FEAT + t];
  const float tv = tf[b * FEAT + t];
  float ss = sv * sv, tt = tv * tv, st = sv * tv;
#pragma unroll
  for (int m = 1; m < 64; m <<= 1) {
    ss += __shfl_xor(ss, m);
    tt += __shfl_xor(tt, m);
    st += __shfl_xor(st, m);
  }
  __shared__ float sh[6];
  if ((t & 63) == 0) {
    const int w = t >> 6;
    sh[w * 3 + 0] = ss; sh[w * 3 + 1] = tt; sh[w * 3 + 2] = st;
  }
  __syncthreads();
  ss = sh[0] + sh[3]; tt = sh[1] + sh[4]; st = sh[2] + sh[5];
  const float snorm = fmaxf(sqrtf(ss), 1e-12f);
  const float tnorm = fmaxf(sqrtf(tt), 1e-12f);
  s_n[b * FEAT + t] = sv / snorm;
  t_n[b * FEAT + t] = tv / tnorm;
  if (t == 0) pos[b] = st / (snorm * tnorm) * INV_TEMP;
}

// ------ work: copy (blocks < NCOPY, persistent) + negsim (the rest) --------
// Copy blocks: cached loads (warm L2/L3 for the gather, same array) +
// nontemporal stores (dst never re-read).
// Negsim blocks: 2 k's per wave-load -- lanes 0-31 carry k0, lanes 32-63
// carry k1, each lane a float4 of features. One dwordx4 load = one 512B row
// per half-wave (coalesced). Reduction = 5 shfl_xor levels within halves.
__global__ __launch_bounds__(256) void work_kernel(
    const float* __restrict__ neg, const int* __restrict__ nidx,
    const float* __restrict__ s_n, float* __restrict__ sumexp,
    float* __restrict__ dst) {
  if (blockIdx.x < NCOPY) {
    const long n4 = NDATA * (long)FEAT / 4;
    long i = (long)blockIdx.x * blockDim.x + threadIdx.x;
    const long stride = (long)NCOPY * blockDim.x;
    for (; i < n4; i += stride) {
      const f4 v = *((const f4*)neg + i);   // cached load: warms L3 for gather
      float* d = dst + 4 * i;
      __builtin_nontemporal_store(v.x, d + 0);
      __builtin_nontemporal_store(v.y, d + 1);
      __builtin_nontemporal_store(v.z, d + 2);
      __builtin_nontemporal_store(v.w, d + 3);
    }
    return;
  }
  __shared__ float part[4];
  const int blk   = blockIdx.x - NCOPY;
  const int b     = blk >> 3;               // batch row of s
  const int chunk = blk & (CHUNKS - 1);     // which 512-k slice
  const int t     = threadIdx.x;
  const int lane  = t & 63;
  const int w     = t >> 6;                 // wave id (0..3)
  const int half  = lane >> 5;              // 0: k-even, 1: k-odd
  const int fo    = (lane & 31) * 4;        // this lane's feature offset
  const f4 s4 = *(const f4*)(s_n + b * FEAT + fo);
  // wave handles 128 consecutive k's, two per load
  const int kbase = b * NNEG + chunk * (NNEG / CHUNKS) + w * 128;
  float acc = 0.f;
  for (int k0 = 0; k0 < 128; k0 += 16) {    // 8 row-loads in flight (16 k)
    int off[8];
#pragma unroll
    for (int u = 0; u < 8; ++u)
      off[u] = nidx[kbase + k0 + 2 * u + half] * FEAT;  // broadcast per half
    f4 v[8];
#pragma unroll
    for (int u = 0; u < 8; ++u)
      v[u] = *(const f4*)(neg + (long)off[u] + fo);
    float p[8];
#pragma unroll
    for (int u = 0; u < 8; ++u) {
      const f4 m = v[u] * s4;
      p[u] = (m.x + m.y) + (m.z + m.w);
    }
#pragma unroll
    for (int ms = 1; ms <= 16; ms <<= 1) {  // 5 levels, stays within halves
#pragma unroll
      for (int u = 0; u < 8; ++u) p[u] += __shfl_xor(p[u], ms);
    }
    // exp(logit - C) = exp2(cos*K1 - K1); each k's term lands in 32 lanes
#pragma unroll
    for (int u = 0; u < 8; ++u) acc += exp2f(fmaf(p[u], K1, -K1));
  }
  acc *= (1.0f / 32.0f);                    // each k counted in 32 lanes
#pragma unroll
  for (int m = 1; m < 64; m <<= 1) acc += __shfl_xor(acc, m);
  if (lane == 0) part[w] = acc;
  __syncthreads();
  if (t == 0)
    sumexp[blk] = part[0] + part[1] + part[2] + part[3];
}

// ------ finish: block 0 = loss (logsumexp mean); blocks 1..512 = EMA -------
__global__ __launch_bounds__(256) void finish_kernel(
    const float* __restrict__ pos, const float* __restrict__ sumexp,
    const float* __restrict__ neg, const float* __restrict__ t_n,
    const int* __restrict__ indices, float* __restrict__ out) {
  const int t = threadIdx.x;
  if (blockIdx.x == 0) {
    float lsum = 0.f;
#pragma unroll
    for (int r = t; r < BATCH; r += 256) {
      const float p = pos[r];
      float tot = exp2f(fmaf(p, LOG2E, -K1));  // exp(p - C)
#pragma unroll
      for (int c = 0; c < CHUNKS; ++c) tot += sumexp[r * CHUNKS + c];
      lsum += INV_TEMP + log2f(tot) * LN2 - p; // C + ln(tot) - p
    }
#pragma unroll
    for (int m = 1; m < 64; m <<= 1) lsum += __shfl_xor(lsum, m);
    __shared__ float sh[4];
    if ((t & 63) == 0) sh[t >> 6] = lsum;
    __syncthreads();
    if (t == 0) out[0] = (sh[0] + sh[1] + sh[2] + sh[3]) / (float)BATCH;
    return;
  }
  // ---- EMA update with last-writer-wins, row b ----
  const int b = blockIdx.x - 1;
  float* dst = out + 1;
  __shared__ int sidx[BATCH];
  __shared__ int flag;
  if (t == 0) flag = 0;
  for (int j = t; j < BATCH; j += 256) sidx[j] = indices[j];
  __syncthreads();
  const int idx = sidx[b];
  int later = 0;
  for (int j = t; j < BATCH; j += 256)
    if (j > b && sidx[j] == idx) later = 1;
  if (later) flag = 1;  // benign same-value race
  __syncthreads();
  if (flag) return;     // a later batch element writes this row (last wins)
  float u = 0.f, uu = 0.f;
  if (t < FEAT) {
    u = 0.5f * neg[(long)idx * FEAT + t] + 0.5f * t_n[b * FEAT + t];
    uu = u * u;
  }
#pragma unroll
  for (int m = 1; m < 64; m <<= 1) uu += __shfl_xor(uu, m);
  __shared__ float sh2[2];
  if (t == 0 || t == 64) sh2[t >> 6] = uu;
  __syncthreads();
  if (t < FEAT) {
    const float nrm = fmaxf(sqrtf(sh2[0] + sh2[1]), 1e-12f);
    dst[(long)idx * FEAT + t] = u / nrm;
  }
}

extern "C" void kernel_launch(void* const* d_in, const int* in_sizes, int n_in,
                              void* d_out, int out_size, void* d_ws, size_t ws_size,
                              hipStream_t stream) {
  const float* student   = (const float*)d_in[0];
  const float* teacher   = (const float*)d_in[1];
  const float* negatives = (const float*)d_in[2];
  const int*   indices   = (const int*)d_in[3];
  const int*   neg_idx   = (const int*)d_in[4];
  float* out = (float*)d_out;

  float* ws     = (float*)d_ws;
  float* s_n    = ws;                        // [512*128]
  float* t_n    = s_n + BATCH * FEAT;        // [512*128]
  float* pos    = t_n + BATCH * FEAT;        // [512]
  float* sumexp = pos + BATCH;               // [512*CHUNKS]

  prep_kernel<<<BATCH, 128, 0, stream>>>(student, teacher, s_n, t_n, pos);
  work_kernel<<<NCOPY + BATCH * CHUNKS, 256, 0, stream>>>(
      negatives, neg_idx, s_n, sumexp, out + 1);
  finish_kernel<<<1 + BATCH, 256, 0, stream>>>(
      pos, sumexp, negatives, t_n, indices, out);
}